// Round 15
// baseline (373.172 us; speedup 1.0000x reference)
//
#include <hip/hip_runtime.h>
#include <hip/hip_bf16.h>
#include <math.h>

// Fused QKV(+bias) -> RoPE -> 4-head causal attention -> FC2(+bias) -> SiLU
// B=2048, L=119, D=128, H=4, HD=32. fp32 in/out, bf16 MFMA internally.
// Head split: model channel c = d*4 + h. Head merge: out channel c' = h*32 + d.
//
// Round 14: R9 base (221.8us verified best) + L2-redundancy cuts, spill-safe.
//  - Wf2b staged to LDS once per block (32KB coop copy issued after the QKV
//    barrier -> latency hidden under attention; consumed after the existing
//    attention->FC2 barrier). L2 reads 256KB -> 32KB per block; FC2's 32
//    per-wave L2 loads become ds_read_b128.
//  - tabL staging prologue dropped; RoPE table read per-lane from L2 in the
//    QKV epilogue (R8 precedent, perf-neutral) -> no block-start barrier.
//  - Everything else BYTE-IDENTICAL to R9: stride 40 (16B-aligned b128),
//    phase-scoped register arrays (R10/R11 spill lesson), y via out.
// Eliminated theories: occupancy (R6), LDS size (R7), bank conflicts
// (R9->R13 9.5M->1.6M no effect), code size / I-cache (R13: rolled = slower).
// Layouts (m74/m101): 32x32 C/D col=lane&31, row=(reg&3)+8*(reg>>2)+4*(lane>>5).
// A: row=lane&31, k=(lane>>5)*8+j. B: col=lane&31, same k.
// LDS: qs/ksm 2x40,960 + vT 32,768 + Wf2bL 32,768 = 147,456 B.

#define L_SEQ 119
#define D_MODEL 128
#define SCALE 0.17677669529663687f  // 1/sqrt(32)
#define NEGINF -1e30f

typedef __bf16 bf16x8 __attribute__((ext_vector_type(8)));
typedef __bf16 bf16x2 __attribute__((ext_vector_type(2)));
typedef float f32x4 __attribute__((ext_vector_type(4)));
typedef float f32x16 __attribute__((ext_vector_type(16)));

__global__ void rope_tab_kernel(unsigned* __restrict__ tabu) {
  int i = blockIdx.x * blockDim.x + threadIdx.x;
  if (i >= L_SEQ * 64) return;
  int l = i >> 6, j = i & 63;
  float inv = 1.0f / powf(10000.0f, (float)(2 * j) / 128.0f);
  float f = (float)l * inv;
  union { bf16x2 v; unsigned u; } cs;
  cs.v[0] = (__bf16)cosf(f);
  cs.v[1] = (__bf16)sinf(f);
  tabu[i] = cs.u;
}

// Wb: A-operand frags for QKV (A=W). flat = ((nt*8 + ks)*64 + lane)*8 + j
//   row chan d = lane&31 (tile nt = h*3+qkv), k = ks*16 + (lane>>5)*8 + j
__global__ void wprep_kernel(const float* __restrict__ Wqkv,
                             const float* __restrict__ bqkv,
                             __bf16* __restrict__ Wb, float* __restrict__ bb2) {
  int i = blockIdx.x * 256 + threadIdx.x;  // 0..49151
  int j = i & 7, lane = (i >> 3) & 63, ks = (i >> 9) & 7, nt = i >> 12;
  int d = lane & 31;
  int h = nt / 3, qkv = nt % 3;
  int k = ks * 16 + (lane >> 5) * 8 + j;
  Wb[i] = (__bf16)Wqkv[(qkv * 128 + d * 4 + h) * 128 + k];
  if (i < 384) {
    int nt2 = i >> 5, dd = i & 31;
    bb2[i] = bqkv[(nt2 % 3) * 128 + dd * 4 + (nt2 / 3)];
  }
}

// Wfc2 B-frags (16x16x32 path): flat = ((nt*4 + kb)*64 + lane)*8 + j
__global__ void wprep2_kernel(const float* __restrict__ Wfc2,
                              __bf16* __restrict__ Wf2b) {
  int i = blockIdx.x * 256 + threadIdx.x;  // 0..16383
  int j = i & 7, lane = (i >> 3) & 63, kb = (i >> 9) & 3, nt = i >> 11;
  int n = nt * 16 + (lane & 15);
  int k = kb * 32 + (lane >> 4) * 8 + j;
  Wf2b[i] = (__bf16)Wfc2[n * 128 + k];
}

__global__ __launch_bounds__(512) void fused_all(
    const float* __restrict__ x, const __bf16* __restrict__ Wb,
    const float* __restrict__ bb2, const unsigned* __restrict__ tabu,
    const __bf16* __restrict__ Wf2b, const float* __restrict__ bfc2,
    float* __restrict__ out) {
  __shared__ __align__(16) __bf16 qs[4 * 128 * 40];    // 40,960 B
  __shared__ __align__(16) __bf16 ksm[4 * 128 * 40];   // 40,960 B
  __shared__ __align__(16) __bf16 vT[4 * 32 * 128];    // 32,768 B (XOR-swz)
  __shared__ __align__(16) __bf16 Wf2bL[16384];        // 32,768 B (staged)

  const int t = threadIdx.x, b = blockIdx.x;
  const int lane = t & 63, wv = t >> 6;
  const int ln31 = lane & 31, hi = lane >> 5;

  // ---- zero vT tail cols 119..127 (disjoint from epilogue writes; read only
  // after the QKV-end barrier -> no early barrier needed)
  for (int i = t; i < 4 * 32 * 9; i += 512) {
    int hd = i / 9, cc = L_SEQ + i % 9, d = hd & 31;
    vT[hd * 128 + (cc ^ ((d & 7) << 3))] = (__bf16)0.0f;
  }

  // ======== QKV: wave -> Mtile (wv&3), Ntile-group (wv>>2)*6 .. +5 ========
  const int mt = wv & 3, g2 = wv >> 2;
  const int l_me = mt * 32 + ln31;  // this lane's sequence row (col of C)
  const bool live = (l_me < L_SEQ);
  {
    int xr = live ? l_me : (L_SEQ - 1);
    const float* xrow = x + ((size_t)b * L_SEQ + xr) * 128;
    bf16x8 af[8];
#pragma unroll
    for (int ks = 0; ks < 8; ++ks) {
      float4 lo = *(const float4*)&xrow[ks * 16 + hi * 8];
      float4 hi4 = *(const float4*)&xrow[ks * 16 + hi * 8 + 4];
      bf16x8 v;
      v[0] = (__bf16)lo.x; v[1] = (__bf16)lo.y; v[2] = (__bf16)lo.z; v[3] = (__bf16)lo.w;
      v[4] = (__bf16)hi4.x; v[5] = (__bf16)hi4.y; v[6] = (__bf16)hi4.z; v[7] = (__bf16)hi4.w;
      af[ks] = v;
    }
#pragma unroll
    for (int r = 0; r < 3; ++r) {
      const int nt0 = g2 * 6 + 2 * r, nt1 = nt0 + 1;
      f32x16 a0 = {}, a1 = {};
#pragma unroll
      for (int ks = 0; ks < 8; ++ks) {
        bf16x8 wf0 = *(const bf16x8*)&Wb[(((nt0 * 8 + ks) * 64) + lane) * 8];
        bf16x8 wf1 = *(const bf16x8*)&Wb[(((nt1 * 8 + ks) * 64) + lane) * 8];
        a0 = __builtin_amdgcn_mfma_f32_32x32x16_bf16(wf0, af[ks], a0, 0, 0, 0);
        a1 = __builtin_amdgcn_mfma_f32_32x32x16_bf16(wf1, af[ks], a1, 0, 0, 0);
      }
      // epilogues
#pragma unroll
      for (int e = 0; e < 2; ++e) {
        const int nt = e ? nt1 : nt0;
        const f32x16& A = e ? a1 : a0;
        const int h = nt / 3, qkv = nt % 3;
        if (qkv < 2) {  // q or k: RoPE in-lane on reg pairs (rg, rg+8)
          __bf16* base = (qkv == 0) ? qs : ksm;
          if (live) {
#pragma unroll
            for (int rg = 0; rg < 8; ++rg) {
              const int c_lo = (rg & 3) + 8 * (rg >> 2);
              int d = c_lo + 4 * hi;  // 0..15
              union { bf16x2 v; unsigned u; } cs;
              cs.u = tabu[l_me * 64 + 4 * d + h];  // L2 (R8 precedent)
              float c = (float)cs.v[0], s = (float)cs.v[1];
              float v1 = A[rg] + bb2[nt * 32 + d];
              float v2 = A[rg + 8] + bb2[nt * 32 + d + 16];
              if (qkv == 0) { v1 *= SCALE; v2 *= SCALE; }
              union { bf16x2 v; unsigned u; } pk;
              pk.v[0] = (__bf16)(v1 * c + v2 * s);
              pk.v[1] = (__bf16)(v2 * c - v1 * s);
              *(unsigned*)&base[(h * 128 + l_me) * 40 + 2 * d] = pk.u;
            }
          }
        } else {  // v: write vT[h][d][l] XOR-swizzled
          if (live) {
#pragma unroll
            for (int rg = 0; rg < 16; ++rg) {
              const int d = (rg & 3) + 8 * (rg >> 2) + 4 * hi;  // 0..31
              float val = A[rg] + bb2[nt * 32 + d];
              vT[(h * 32 + d) * 128 + (l_me ^ ((d & 7) << 3))] = (__bf16)val;
            }
          }
        }
      }
    }
  }
  __syncthreads();

  // ---- stage Wf2b -> LDS (latency hides under attention; consumed after the
  // attention->FC2 barrier). 512 thr x 4 uint4 = 32KB, fully coalesced.
  {
    const uint4* wsrc = (const uint4*)Wf2b;
    uint4* wd = (uint4*)Wf2bL;
    wd[t] = wsrc[t];
    wd[512 + t] = wsrc[512 + t];
    wd[1024 + t] = wsrc[1024 + t];
    wd[1536 + t] = wsrc[1536 + t];
  }

  // ======== attention: wave -> head (wv>>1); tasks qt = {wv&1, 3-(wv&1)} ====
  {
    const int h = wv >> 1;
#pragma unroll
    for (int ts = 0; ts < 2; ++ts) {
      const int qt = ts ? (3 - (wv & 1)) : (wv & 1);
      bf16x8 qf0 = *(const bf16x8*)&qs[(h * 128 + qt * 32 + ln31) * 40 + hi * 8];
      bf16x8 qf1 = *(const bf16x8*)&qs[(h * 128 + qt * 32 + ln31) * 40 + 16 + hi * 8];
      f32x16 s[4];
#pragma unroll
      for (int kt = 0; kt < 4; ++kt) {
        if (kt <= qt) {
          bf16x8 kf0 = *(const bf16x8*)&ksm[(h * 128 + kt * 32 + ln31) * 40 + hi * 8];
          bf16x8 kf1 = *(const bf16x8*)&ksm[(h * 128 + kt * 32 + ln31) * 40 + 16 + hi * 8];
          f32x16 z = {};
          z = __builtin_amdgcn_mfma_f32_32x32x16_bf16(kf0, qf0, z, 0, 0, 0);
          s[kt] = __builtin_amdgcn_mfma_f32_32x32x16_bf16(kf1, qf1, z, 0, 0, 0);
        }
      }
      // causal mask (diagonal tile only; garbage keys >=119 are key>query)
#pragma unroll
      for (int rg = 0; rg < 16; ++rg) {
        const int c_lo = (rg & 3) + 8 * (rg >> 2);
        int crow = c_lo + 4 * hi;
        s[qt][rg] = (crow <= ln31) ? s[qt][rg] : NEGINF;
      }
      float mx = NEGINF;
#pragma unroll
      for (int kt = 0; kt < 4; ++kt)
        if (kt <= qt)
#pragma unroll
          for (int rg = 0; rg < 16; ++rg) mx = fmaxf(mx, s[kt][rg]);
      mx = fmaxf(mx, __shfl_xor(mx, 32));
      float sum = 0.0f;
#pragma unroll
      for (int kt = 0; kt < 4; ++kt)
        if (kt <= qt)
#pragma unroll
          for (int rg = 0; rg < 16; ++rg) {
            s[kt][rg] = __expf(s[kt][rg] - mx);
            sum += s[kt][rg];
          }
      sum += __shfl_xor(sum, 32);
      float inv = 1.0f / sum;
      unsigned pk[4][8];
#pragma unroll
      for (int kt = 0; kt < 4; ++kt) {
        if (kt <= qt) {
#pragma unroll
          for (int p = 0; p < 8; ++p) {
            union { bf16x2 v; unsigned u; } w;
            w.v[0] = (__bf16)(s[kt][2 * p] * inv);
            w.v[1] = (__bf16)(s[kt][2 * p + 1] * inv);
            pk[kt][p] = w.u;
          }
        }
      }
      f32x16 o = {};
#pragma unroll
      for (int kt = 0; kt < 4; ++kt) {
        if (kt <= qt) {
#pragma unroll
          for (int m = 0; m < 2; ++m) {
            unsigned f0 = (unsigned)__shfl_xor((int)pk[kt][4 * m + 0], 32);
            unsigned f1 = (unsigned)__shfl_xor((int)pk[kt][4 * m + 1], 32);
            unsigned f2 = (unsigned)__shfl_xor((int)pk[kt][4 * m + 2], 32);
            unsigned f3 = (unsigned)__shfl_xor((int)pk[kt][4 * m + 3], 32);
            union { unsigned w[4]; bf16x8 v; } Aw;
            Aw.w[0] = hi ? f2 : pk[kt][4 * m + 0];
            Aw.w[1] = hi ? f3 : pk[kt][4 * m + 1];
            Aw.w[2] = hi ? pk[kt][4 * m + 2] : f0;
            Aw.w[3] = hi ? pk[kt][4 * m + 3] : f1;
            bf16x8 vf = *(const bf16x8*)&vT[(h * 32 + ln31) * 128 +
                ((kt * 32 + m * 16 + hi * 8) ^ ((ln31 & 7) << 3))];
            o = __builtin_amdgcn_mfma_f32_32x32x16_bf16(Aw.v, vf, o, 0, 0, 0);
          }
        }
      }
#pragma unroll
      for (int rg = 0; rg < 16; ++rg) {
        const int c_lo = (rg & 3) + 8 * (rg >> 2);
        int l = qt * 32 + c_lo + 4 * hi;
        if (l < L_SEQ)
          out[((size_t)b * L_SEQ + l) * 128 + h * 32 + ln31] = o[rg];
      }
    }
  }
  __syncthreads();

  // ======== FC2 + bias + SiLU: y from out (L2-hot), W from LDS ========
  {
    const int ln15 = lane & 15, kg = lane >> 4;
    int yr = wv * 16 + ln15;
    if (yr > L_SEQ - 1) yr = L_SEQ - 1;
    const float* yrow = out + ((size_t)b * L_SEQ + yr) * 128;
    bf16x8 af2[4];
#pragma unroll
    for (int kb = 0; kb < 4; ++kb) {
      float4 lo = *(const float4*)&yrow[kb * 32 + kg * 8];
      float4 hi4 = *(const float4*)&yrow[kb * 32 + kg * 8 + 4];
      bf16x8 v;
      v[0] = (__bf16)lo.x; v[1] = (__bf16)lo.y; v[2] = (__bf16)lo.z; v[3] = (__bf16)lo.w;
      v[4] = (__bf16)hi4.x; v[5] = (__bf16)hi4.y; v[6] = (__bf16)hi4.z; v[7] = (__bf16)hi4.w;
      af2[kb] = v;
    }
    float bc[8];
#pragma unroll
    for (int nt = 0; nt < 8; ++nt) bc[nt] = bfc2[nt * 16 + ln15];
    f32x4 acc2[8] = {};
#pragma unroll
    for (int nt = 0; nt < 8; ++nt)
#pragma unroll
      for (int kb = 0; kb < 4; ++kb)
        acc2[nt] = __builtin_amdgcn_mfma_f32_16x16x32_bf16(
            af2[kb], *(const bf16x8*)&Wf2bL[(((nt * 4 + kb) * 64) + lane) * 8],
            acc2[nt], 0, 0, 0);
#pragma unroll
    for (int nt = 0; nt < 8; ++nt)
#pragma unroll
      for (int r = 0; r < 4; ++r) {
        int row = wv * 16 + kg * 4 + r, c = nt * 16 + ln15;
        if (row < L_SEQ) {
          float vv = acc2[nt][r] + bc[nt];
          out[((size_t)b * L_SEQ + row) * 128 + c] = vv / (1.0f + __expf(-vv));
        }
      }
  }
}

extern "C" void kernel_launch(void* const* d_in, const int* in_sizes, int n_in,
                              void* d_out, int out_size, void* d_ws,
                              size_t ws_size, hipStream_t stream) {
  const float* x = (const float*)d_in[0];
  const float* Wqkv = (const float*)d_in[1];
  const float* bqkv = (const float*)d_in[2];
  const float* Wfc2 = (const float*)d_in[3];
  const float* bfc2 = (const float*)d_in[4];
  float* out = (float*)d_out;

  char* ws = (char*)d_ws;
  unsigned* tabu = (unsigned*)ws;                        // 30,464 B (pad 30,720)
  __bf16* Wb = (__bf16*)(ws + 30720);                    // 98,304 B
  float* bb2 = (float*)(ws + 30720 + 98304);             //  1,536 B
  __bf16* Wf2b = (__bf16*)(ws + 30720 + 98304 + 1536);   // 32,768 B (end 163,328)

  const int B = in_sizes[0] / (L_SEQ * D_MODEL);  // 2048
  rope_tab_kernel<<<(L_SEQ * 64 + 255) / 256, 256, 0, stream>>>(tabu);
  wprep_kernel<<<192, 256, 0, stream>>>(Wqkv, bqkv, Wb, bb2);
  wprep2_kernel<<<64, 256, 0, stream>>>(Wfc2, Wf2b);
  fused_all<<<B, 512, 0, stream>>>(x, Wb, bb2, tabu, Wf2b, bfc2, out);
}

// Round 16
// 274.760 us; speedup vs baseline: 1.3582x; 1.3582x over previous
//
#include <hip/hip_runtime.h>
#include <hip/hip_bf16.h>
#include <math.h>

// Fused QKV(+bias) -> RoPE -> 4-head causal attention -> FC2(+bias) -> SiLU
// B=2048, L=119, D=128, H=4, HD=32. fp32 in/out, bf16 MFMA internally.
// Head split: model channel c = d*4 + h. Head merge: out channel c' = h*32 + d.
//
// Round 15: R9 math (verified 221.8us) restructured into TWO head-group
// phases ({0,1} then {2,3}) to reach 2 blocks/CU. Timing model from R5-R14:
// occupancy 23% = 1 block/CU -> 8 blocks per CU run SERIALLY, each paying its
// full latency chain; R6's flat result came from 4x redundant work. Here the
// only extra work is af reload per phase (L2-hot) + 2 barriers; 2 co-resident
// blocks overlap each other's stalls.
//  - LDS 57,344 B: qs/ks [2][128][40], vT [2][32][128] XOR-swz; tabL dropped
//    (tab from L2; values identical).
//  - Attention: per phase 8 tasks (lh=wv&1, qt=wv>>1), runtime-uniform qt
//    (R13-proven spill-clean codegen). FC2 verbatim R9.
//  - ALL register arrays phase-scoped (R10/R11/R14 spill lesson).
// Layouts (m74/m101): 32x32 C/D col=lane&31, row=(reg&3)+8*(reg>>2)+4*(lane>>5).
// A: row=lane&31, k=(lane>>5)*8+j. B: col=lane&31, same k.

#define L_SEQ 119
#define D_MODEL 128
#define SCALE 0.17677669529663687f  // 1/sqrt(32)
#define NEGINF -1e30f

typedef __bf16 bf16x8 __attribute__((ext_vector_type(8)));
typedef __bf16 bf16x2 __attribute__((ext_vector_type(2)));
typedef float f32x4 __attribute__((ext_vector_type(4)));
typedef float f32x16 __attribute__((ext_vector_type(16)));

__global__ void rope_tab_kernel(unsigned* __restrict__ tabu) {
  int i = blockIdx.x * blockDim.x + threadIdx.x;
  if (i >= L_SEQ * 64) return;
  int l = i >> 6, j = i & 63;
  float inv = 1.0f / powf(10000.0f, (float)(2 * j) / 128.0f);
  float f = (float)l * inv;
  union { bf16x2 v; unsigned u; } cs;
  cs.v[0] = (__bf16)cosf(f);
  cs.v[1] = (__bf16)sinf(f);
  tabu[i] = cs.u;
}

// Wb: A-operand frags for QKV (A=W). flat = ((nt*8 + ks)*64 + lane)*8 + j
//   row chan d = lane&31 (tile nt = h*3+qkv), k = ks*16 + (lane>>5)*8 + j
__global__ void wprep_kernel(const float* __restrict__ Wqkv,
                             const float* __restrict__ bqkv,
                             __bf16* __restrict__ Wb, float* __restrict__ bb2) {
  int i = blockIdx.x * 256 + threadIdx.x;  // 0..49151
  int j = i & 7, lane = (i >> 3) & 63, ks = (i >> 9) & 7, nt = i >> 12;
  int d = lane & 31;
  int h = nt / 3, qkv = nt % 3;
  int k = ks * 16 + (lane >> 5) * 8 + j;
  Wb[i] = (__bf16)Wqkv[(qkv * 128 + d * 4 + h) * 128 + k];
  if (i < 384) {
    int nt2 = i >> 5, dd = i & 31;
    bb2[i] = bqkv[(nt2 % 3) * 128 + dd * 4 + (nt2 / 3)];
  }
}

// Wfc2 B-frags (16x16x32 path): flat = ((nt*4 + kb)*64 + lane)*8 + j
__global__ void wprep2_kernel(const float* __restrict__ Wfc2,
                              __bf16* __restrict__ Wf2b) {
  int i = blockIdx.x * 256 + threadIdx.x;  // 0..16383
  int j = i & 7, lane = (i >> 3) & 63, kb = (i >> 9) & 3, nt = i >> 11;
  int n = nt * 16 + (lane & 15);
  int k = kb * 32 + (lane >> 4) * 8 + j;
  Wf2b[i] = (__bf16)Wfc2[n * 128 + k];
}

__global__ __launch_bounds__(512) void fused_all(
    const float* __restrict__ x, const __bf16* __restrict__ Wb,
    const float* __restrict__ bb2, const unsigned* __restrict__ tabu,
    const __bf16* __restrict__ Wf2b, const float* __restrict__ bfc2,
    float* __restrict__ out) {
  __shared__ __align__(16) __bf16 qs[2 * 128 * 40];   // 20,480 B
  __shared__ __align__(16) __bf16 ksm[2 * 128 * 40];  // 20,480 B
  __shared__ __align__(16) __bf16 vT[2 * 32 * 128];   // 16,384 B (XOR-swz)

  const int t = threadIdx.x, b = blockIdx.x;
  const int lane = t & 63, wv = t >> 6;
  const int ln31 = lane & 31, hi = lane >> 5;
  const int mt = wv & 3, hg = wv >> 2;   // QKV: M-tile, local head
  const int l_me = mt * 32 + ln31;
  const bool live = (l_me < L_SEQ);

  // ---- zero vT tail cols 119..127 (written once; data cols l<119 only ever
  // rewritten, so zeros persist across both phases)
  for (int i = t; i < 2 * 32 * 9; i += 512) {
    int hd = i / 9, cc = L_SEQ + i % 9, d = hd & 31;
    vT[hd * 128 + (cc ^ ((d & 7) << 3))] = (__bf16)0.0f;
  }

#pragma unroll
  for (int g = 0; g < 2; ++g) {
    if (g) __syncthreads();  // prior phase's attention done reading LDS

    // ======== QKV phase g: wave (mt, hg) -> tiles of head 2g+hg ========
    {
      int xr = live ? l_me : (L_SEQ - 1);
      const float* xrow = x + ((size_t)b * L_SEQ + xr) * 128;
      bf16x8 af[8];
#pragma unroll
      for (int ks = 0; ks < 8; ++ks) {
        float4 lo = *(const float4*)&xrow[ks * 16 + hi * 8];
        float4 hi4 = *(const float4*)&xrow[ks * 16 + hi * 8 + 4];
        bf16x8 v;
        v[0] = (__bf16)lo.x; v[1] = (__bf16)lo.y; v[2] = (__bf16)lo.z; v[3] = (__bf16)lo.w;
        v[4] = (__bf16)hi4.x; v[5] = (__bf16)hi4.y; v[6] = (__bf16)hi4.z; v[7] = (__bf16)hi4.w;
        af[ks] = v;
      }
      const int h = 2 * g + hg;        // global head
      const int ntq = h * 3;           // q tile; +1 = k; +2 = v
      // ---- q,k pair (both need RoPE)
      {
        f32x16 a0 = {}, a1 = {};
#pragma unroll
        for (int ks = 0; ks < 8; ++ks) {
          bf16x8 wf0 = *(const bf16x8*)&Wb[(((ntq * 8 + ks) * 64) + lane) * 8];
          bf16x8 wf1 = *(const bf16x8*)&Wb[((((ntq + 1) * 8 + ks) * 64) + lane) * 8];
          a0 = __builtin_amdgcn_mfma_f32_32x32x16_bf16(wf0, af[ks], a0, 0, 0, 0);
          a1 = __builtin_amdgcn_mfma_f32_32x32x16_bf16(wf1, af[ks], a1, 0, 0, 0);
        }
#pragma unroll
        for (int e = 0; e < 2; ++e) {
          const f32x16& A = e ? a1 : a0;
          const int nt = ntq + e;
          __bf16* base = e ? ksm : qs;
          if (live) {
#pragma unroll
            for (int rg = 0; rg < 8; ++rg) {
              const int c_lo = (rg & 3) + 8 * (rg >> 2);
              int d = c_lo + 4 * hi;  // 0..15
              union { bf16x2 v; unsigned u; } cs;
              cs.u = tabu[l_me * 64 + 4 * d + h];
              float c = (float)cs.v[0], s = (float)cs.v[1];
              float v1 = A[rg] + bb2[nt * 32 + d];
              float v2 = A[rg + 8] + bb2[nt * 32 + d + 16];
              if (e == 0) { v1 *= SCALE; v2 *= SCALE; }
              union { bf16x2 v; unsigned u; } pk;
              pk.v[0] = (__bf16)(v1 * c + v2 * s);
              pk.v[1] = (__bf16)(v2 * c - v1 * s);
              *(unsigned*)&base[(hg * 128 + l_me) * 40 + 2 * d] = pk.u;
            }
          }
        }
      }
      // ---- v tile
      {
        f32x16 a2 = {};
#pragma unroll
        for (int ks = 0; ks < 8; ++ks) {
          bf16x8 wf2 = *(const bf16x8*)&Wb[((((ntq + 2) * 8 + ks) * 64) + lane) * 8];
          a2 = __builtin_amdgcn_mfma_f32_32x32x16_bf16(wf2, af[ks], a2, 0, 0, 0);
        }
        if (live) {
#pragma unroll
          for (int rg = 0; rg < 16; ++rg) {
            const int d = (rg & 3) + 8 * (rg >> 2) + 4 * hi;  // 0..31
            float val = a2[rg] + bb2[(ntq + 2) * 32 + d];
            vT[(hg * 32 + d) * 128 + (l_me ^ ((d & 7) << 3))] = (__bf16)val;
          }
        }
      }
    }
    __syncthreads();

    // ======== attention phase g: wave -> (lh = wv&1, qt = wv>>1) ========
    {
      const int lh = wv & 1, qt = wv >> 1;  // runtime wave-uniform (R13-clean)
      const int h = 2 * g + lh;
      bf16x8 qf0 = *(const bf16x8*)&qs[(lh * 128 + qt * 32 + ln31) * 40 + hi * 8];
      bf16x8 qf1 = *(const bf16x8*)&qs[(lh * 128 + qt * 32 + ln31) * 40 + 16 + hi * 8];
      f32x16 s[4];
#pragma unroll
      for (int kt = 0; kt < 4; ++kt) {
        if (kt <= qt) {
          bf16x8 kf0 = *(const bf16x8*)&ksm[(lh * 128 + kt * 32 + ln31) * 40 + hi * 8];
          bf16x8 kf1 = *(const bf16x8*)&ksm[(lh * 128 + kt * 32 + ln31) * 40 + 16 + hi * 8];
          f32x16 z = {};
          z = __builtin_amdgcn_mfma_f32_32x32x16_bf16(kf0, qf0, z, 0, 0, 0);
          s[kt] = __builtin_amdgcn_mfma_f32_32x32x16_bf16(kf1, qf1, z, 0, 0, 0);
          if (kt == qt) {  // diagonal mask; s[] index compile-time (rule #20)
#pragma unroll
            for (int rg = 0; rg < 16; ++rg) {
              const int c_lo = (rg & 3) + 8 * (rg >> 2);
              int crow = c_lo + 4 * hi;
              s[kt][rg] = (crow <= ln31) ? s[kt][rg] : NEGINF;
            }
          }
        }
      }
      float mx = NEGINF;
#pragma unroll
      for (int kt = 0; kt < 4; ++kt)
        if (kt <= qt)
#pragma unroll
          for (int rg = 0; rg < 16; ++rg) mx = fmaxf(mx, s[kt][rg]);
      mx = fmaxf(mx, __shfl_xor(mx, 32));
      float sum = 0.0f;
#pragma unroll
      for (int kt = 0; kt < 4; ++kt)
        if (kt <= qt)
#pragma unroll
          for (int rg = 0; rg < 16; ++rg) {
            s[kt][rg] = __expf(s[kt][rg] - mx);
            sum += s[kt][rg];
          }
      sum += __shfl_xor(sum, 32);
      float inv = 1.0f / sum;
      unsigned pk[4][8];
#pragma unroll
      for (int kt = 0; kt < 4; ++kt) {
        if (kt <= qt) {
#pragma unroll
          for (int p = 0; p < 8; ++p) {
            union { bf16x2 v; unsigned u; } w;
            w.v[0] = (__bf16)(s[kt][2 * p] * inv);
            w.v[1] = (__bf16)(s[kt][2 * p + 1] * inv);
            pk[kt][p] = w.u;
          }
        }
      }
      f32x16 o = {};
#pragma unroll
      for (int kt = 0; kt < 4; ++kt) {
        if (kt <= qt) {
#pragma unroll
          for (int m = 0; m < 2; ++m) {
            unsigned f0 = (unsigned)__shfl_xor((int)pk[kt][4 * m + 0], 32);
            unsigned f1 = (unsigned)__shfl_xor((int)pk[kt][4 * m + 1], 32);
            unsigned f2 = (unsigned)__shfl_xor((int)pk[kt][4 * m + 2], 32);
            unsigned f3 = (unsigned)__shfl_xor((int)pk[kt][4 * m + 3], 32);
            union { unsigned w[4]; bf16x8 v; } Aw;
            Aw.w[0] = hi ? f2 : pk[kt][4 * m + 0];
            Aw.w[1] = hi ? f3 : pk[kt][4 * m + 1];
            Aw.w[2] = hi ? pk[kt][4 * m + 2] : f0;
            Aw.w[3] = hi ? pk[kt][4 * m + 3] : f1;
            bf16x8 vf = *(const bf16x8*)&vT[(lh * 32 + ln31) * 128 +
                ((kt * 32 + m * 16 + hi * 8) ^ ((ln31 & 7) << 3))];
            o = __builtin_amdgcn_mfma_f32_32x32x16_bf16(Aw.v, vf, o, 0, 0, 0);
          }
        }
      }
#pragma unroll
      for (int rg = 0; rg < 16; ++rg) {
        const int c_lo = (rg & 3) + 8 * (rg >> 2);
        int l = qt * 32 + c_lo + 4 * hi;
        if (l < L_SEQ)
          out[((size_t)b * L_SEQ + l) * 128 + h * 32 + ln31] = o[rg];
      }
    }
  }
  __syncthreads();  // all y writes drained (vmcnt) -> L2-visible to block

  // ======== FC2 + bias + SiLU (verbatim R9) ========
  {
    const int ln15 = lane & 15, kg = lane >> 4;
    int yr = wv * 16 + ln15;
    if (yr > L_SEQ - 1) yr = L_SEQ - 1;
    const float* yrow = out + ((size_t)b * L_SEQ + yr) * 128;
    bf16x8 af2[4];
#pragma unroll
    for (int kb = 0; kb < 4; ++kb) {
      float4 lo = *(const float4*)&yrow[kb * 32 + kg * 8];
      float4 hi4 = *(const float4*)&yrow[kb * 32 + kg * 8 + 4];
      bf16x8 v;
      v[0] = (__bf16)lo.x; v[1] = (__bf16)lo.y; v[2] = (__bf16)lo.z; v[3] = (__bf16)lo.w;
      v[4] = (__bf16)hi4.x; v[5] = (__bf16)hi4.y; v[6] = (__bf16)hi4.z; v[7] = (__bf16)hi4.w;
      af2[kb] = v;
    }
    float bc[8];
#pragma unroll
    for (int nt = 0; nt < 8; ++nt) bc[nt] = bfc2[nt * 16 + ln15];
    f32x4 acc2[8] = {};
#pragma unroll
    for (int nt = 0; nt < 8; ++nt)
#pragma unroll
      for (int kb = 0; kb < 4; ++kb)
        acc2[nt] = __builtin_amdgcn_mfma_f32_16x16x32_bf16(
            af2[kb], *(const bf16x8*)&Wf2b[(((nt * 4 + kb) * 64) + lane) * 8],
            acc2[nt], 0, 0, 0);
#pragma unroll
    for (int nt = 0; nt < 8; ++nt)
#pragma unroll
      for (int r = 0; r < 4; ++r) {
        int row = wv * 16 + kg * 4 + r, c = nt * 16 + ln15;
        if (row < L_SEQ) {
          float vv = acc2[nt][r] + bc[nt];
          out[((size_t)b * L_SEQ + row) * 128 + c] = vv / (1.0f + __expf(-vv));
        }
      }
  }
}

extern "C" void kernel_launch(void* const* d_in, const int* in_sizes, int n_in,
                              void* d_out, int out_size, void* d_ws,
                              size_t ws_size, hipStream_t stream) {
  const float* x = (const float*)d_in[0];
  const float* Wqkv = (const float*)d_in[1];
  const float* bqkv = (const float*)d_in[2];
  const float* Wfc2 = (const float*)d_in[3];
  const float* bfc2 = (const float*)d_in[4];
  float* out = (float*)d_out;

  char* ws = (char*)d_ws;
  unsigned* tabu = (unsigned*)ws;                        // 30,464 B (pad 30,720)
  __bf16* Wb = (__bf16*)(ws + 30720);                    // 98,304 B
  float* bb2 = (float*)(ws + 30720 + 98304);             //  1,536 B
  __bf16* Wf2b = (__bf16*)(ws + 30720 + 98304 + 1536);   // 32,768 B (end 163,328)

  const int B = in_sizes[0] / (L_SEQ * D_MODEL);  // 2048
  rope_tab_kernel<<<(L_SEQ * 64 + 255) / 256, 256, 0, stream>>>(tabu);
  wprep_kernel<<<192, 256, 0, stream>>>(Wqkv, bqkv, Wb, bb2);
  wprep2_kernel<<<64, 256, 0, stream>>>(Wfc2, Wf2b);
  fused_all<<<B, 512, 0, stream>>>(x, Wb, bb2, tabu, Wf2b, bfc2, out);
}

// Round 17
// 217.644 us; speedup vs baseline: 1.7146x; 1.2624x over previous
//
#include <hip/hip_runtime.h>
#include <hip/hip_bf16.h>
#include <math.h>

// Fused QKV(+bias) -> RoPE -> 4-head causal attention -> FC2(+bias) -> SiLU
// B=2048, L=119, D=128, H=4, HD=32. fp32 in/out, bf16 MFMA internally.
// Head split: model channel c = d*4 + h. Head merge: out channel c' = h*32 + d.
//
// Round 16: R9 fused kernel BYTE-IDENTICAL (verified best, 221.8us; spill-
// clean at VGPR~88). One riskless change: the three prep launches merged into
// one kernel (saves ~2 x 4-6us launch overhead). Occupancy mystery closed:
// gfx950 unified VGPR+AGPR budget -> f32x16 accumulators (64+ AGPRs) put all
// 32x32 variants in the 256-reg class = 8 waves/CU cap; 16x16 variants (R6,
// 64-reg class) reached 44% occupancy and dur was STILL ~205us -> occupancy
// irrelevant for this kernel (confirmed in both register regimes).
// Levers proven null/negative on the ~205us plateau: occupancy (R6/R15),
// LDS footprint (R7), bank conflicts (9.5M->1.6M, R13), code size (R13
// rolled = slower), L2 W-staging (R10/R14: spill-contaminated, R11 same).
// tabL LDS staging is load-bearing (R15 dropped it -> tab becomes a
// 64-cacheline gather in the hot epilogue; part of R15's -70us).
// Layouts (m74/m101): 32x32 C/D col=lane&31, row=(reg&3)+8*(reg>>2)+4*(lane>>5).
// A: row=lane&31, k=(lane>>5)*8+j. B: col=lane&31, same k.
// LDS: qs/ksm [4][128][40] 2x40,960 + vT [4][32][128] 32,768 + tabL [119][65]
// 30,940 = 145,628 B.

#define L_SEQ 119
#define D_MODEL 128
#define SCALE 0.17677669529663687f  // 1/sqrt(32)
#define NEGINF -1e30f

typedef __bf16 bf16x8 __attribute__((ext_vector_type(8)));
typedef __bf16 bf16x2 __attribute__((ext_vector_type(2)));
typedef float f32x4 __attribute__((ext_vector_type(4)));
typedef float f32x16 __attribute__((ext_vector_type(16)));

// ---- single prep kernel: RoPE table + Wb A-frags + bb2 + Wfc2 B-frags ----
// Wb: flat = ((nt*8 + ks)*64 + lane)*8 + j ; nt = h*3+qkv, d = lane&31,
//     k = ks*16 + (lane>>5)*8 + j ; src row = qkv*128 + d*4 + h.
// Wf2b: flat = ((nt*4 + kb)*64 + lane)*8 + j ; n = nt*16+(lane&15),
//     k = kb*32 + (lane>>4)*8 + j.
__global__ void prep_kernel(const float* __restrict__ Wqkv,
                            const float* __restrict__ bqkv,
                            const float* __restrict__ Wfc2,
                            unsigned* __restrict__ tabu,
                            __bf16* __restrict__ Wb, float* __restrict__ bb2,
                            __bf16* __restrict__ Wf2b) {
  int i = blockIdx.x * 256 + threadIdx.x;  // 0..49151
  {  // Wb (all threads)
    int j = i & 7, lane = (i >> 3) & 63, ks = (i >> 9) & 7, nt = i >> 12;
    int d = lane & 31;
    int h = nt / 3, qkv = nt % 3;
    int k = ks * 16 + (lane >> 5) * 8 + j;
    Wb[i] = (__bf16)Wqkv[(qkv * 128 + d * 4 + h) * 128 + k];
  }
  if (i < 384) {  // bb2
    int nt2 = i >> 5, dd = i & 31;
    bb2[i] = bqkv[(nt2 % 3) * 128 + dd * 4 + (nt2 / 3)];
  }
  if (i < 16384) {  // Wf2b
    int j = i & 7, lane = (i >> 3) & 63, kb = (i >> 9) & 3, nt = i >> 11;
    int n = nt * 16 + (lane & 15);
    int k = kb * 32 + (lane >> 4) * 8 + j;
    Wf2b[i] = (__bf16)Wfc2[n * 128 + k];
  }
  if (i < L_SEQ * 64) {  // RoPE table (bf16-rounded, as reference)
    int l = i >> 6, j = i & 63;
    float inv = 1.0f / powf(10000.0f, (float)(2 * j) / 128.0f);
    float f = (float)l * inv;
    union { bf16x2 v; unsigned u; } cs;
    cs.v[0] = (__bf16)cosf(f);
    cs.v[1] = (__bf16)sinf(f);
    tabu[i] = cs.u;
  }
}

__global__ __launch_bounds__(512) void fused_all(
    const float* __restrict__ x, const __bf16* __restrict__ Wb,
    const float* __restrict__ bb2, const unsigned* __restrict__ tabu,
    const __bf16* __restrict__ Wf2b, const float* __restrict__ bfc2,
    float* __restrict__ out) {
  __shared__ __align__(16) __bf16 qs[4 * 128 * 40];   // 40,960 B
  __shared__ __align__(16) __bf16 ksm[4 * 128 * 40];  // 40,960 B
  __shared__ __align__(16) __bf16 vT[4 * 32 * 128];   // 32,768 B (XOR-swizzled)
  __shared__ unsigned tabL[L_SEQ * 65];               // 30,940 B

  const int t = threadIdx.x, b = blockIdx.x;
  const int lane = t & 63, wv = t >> 6;
  const int ln31 = lane & 31, hi = lane >> 5;

  // ---- stage RoPE table (stride 65 words -> conflict-free lane-l reads)
  for (int i = t; i < L_SEQ * 64; i += 512)
    tabL[(i >> 6) * 65 + (i & 63)] = tabu[i];
  // ---- zero vT tail cols 119..127
  for (int i = t; i < 4 * 32 * 9; i += 512) {
    int hd = i / 9, cc = L_SEQ + i % 9, d = hd & 31;
    vT[hd * 128 + (cc ^ ((d & 7) << 3))] = (__bf16)0.0f;
  }
  __syncthreads();

  // ======== QKV: wave -> Mtile (wv&3), Ntile-group (wv>>2)*6 .. +5 ========
  const int mt = wv & 3, g2 = wv >> 2;
  const int l_me = mt * 32 + ln31;  // this lane's sequence row (col of C)
  const bool live = (l_me < L_SEQ);
  {
    int xr = live ? l_me : (L_SEQ - 1);
    const float* xrow = x + ((size_t)b * L_SEQ + xr) * 128;
    bf16x8 af[8];
#pragma unroll
    for (int ks = 0; ks < 8; ++ks) {
      float4 lo = *(const float4*)&xrow[ks * 16 + hi * 8];
      float4 hi4 = *(const float4*)&xrow[ks * 16 + hi * 8 + 4];
      bf16x8 v;
      v[0] = (__bf16)lo.x; v[1] = (__bf16)lo.y; v[2] = (__bf16)lo.z; v[3] = (__bf16)lo.w;
      v[4] = (__bf16)hi4.x; v[5] = (__bf16)hi4.y; v[6] = (__bf16)hi4.z; v[7] = (__bf16)hi4.w;
      af[ks] = v;
    }
#pragma unroll
    for (int r = 0; r < 3; ++r) {
      const int nt0 = g2 * 6 + 2 * r, nt1 = nt0 + 1;
      f32x16 a0 = {}, a1 = {};
#pragma unroll
      for (int ks = 0; ks < 8; ++ks) {
        bf16x8 wf0 = *(const bf16x8*)&Wb[(((nt0 * 8 + ks) * 64) + lane) * 8];
        bf16x8 wf1 = *(const bf16x8*)&Wb[(((nt1 * 8 + ks) * 64) + lane) * 8];
        a0 = __builtin_amdgcn_mfma_f32_32x32x16_bf16(wf0, af[ks], a0, 0, 0, 0);
        a1 = __builtin_amdgcn_mfma_f32_32x32x16_bf16(wf1, af[ks], a1, 0, 0, 0);
      }
      // epilogues (runtime wave-uniform qkv type)
#pragma unroll
      for (int e = 0; e < 2; ++e) {
        const int nt = e ? nt1 : nt0;
        const f32x16& A = e ? a1 : a0;
        const int h = nt / 3, qkv = nt % 3;
        if (qkv < 2) {  // q or k: RoPE in-lane on reg pairs (rg, rg+8)
          __bf16* base = (qkv == 0) ? qs : ksm;
          if (live) {
#pragma unroll
            for (int rg = 0; rg < 8; ++rg) {
              const int c_lo = (rg & 3) + 8 * (rg >> 2);
              int d = c_lo + 4 * hi;  // 0..15
              union { bf16x2 v; unsigned u; } cs;
              cs.u = tabL[l_me * 65 + 4 * d + h];
              float c = (float)cs.v[0], s = (float)cs.v[1];
              float v1 = A[rg] + bb2[nt * 32 + d];
              float v2 = A[rg + 8] + bb2[nt * 32 + d + 16];
              if (qkv == 0) { v1 *= SCALE; v2 *= SCALE; }
              union { bf16x2 v; unsigned u; } pk;
              pk.v[0] = (__bf16)(v1 * c + v2 * s);
              pk.v[1] = (__bf16)(v2 * c - v1 * s);
              *(unsigned*)&base[(h * 128 + l_me) * 40 + 2 * d] = pk.u;
            }
          }
        } else {  // v: write vT[h][d][l] XOR-swizzled
          if (live) {
#pragma unroll
            for (int rg = 0; rg < 16; ++rg) {
              const int d = (rg & 3) + 8 * (rg >> 2) + 4 * hi;  // 0..31
              float val = A[rg] + bb2[nt * 32 + d];
              vT[(h * 32 + d) * 128 + (l_me ^ ((d & 7) << 3))] = (__bf16)val;
            }
          }
        }
      }
    }
  }
  __syncthreads();

  // ======== attention: wave -> head (wv>>1); tasks qt = {wv&1, 3-(wv&1)} ====
  {
    const int h = wv >> 1;
#pragma unroll
    for (int ts = 0; ts < 2; ++ts) {
      const int qt = ts ? (3 - (wv & 1)) : (wv & 1);
      // Q B-frags: col = query = ln31
      bf16x8 qf0 = *(const bf16x8*)&qs[(h * 128 + qt * 32 + ln31) * 40 + hi * 8];
      bf16x8 qf1 = *(const bf16x8*)&qs[(h * 128 + qt * 32 + ln31) * 40 + 16 + hi * 8];
      f32x16 s[4];
#pragma unroll
      for (int kt = 0; kt < 4; ++kt) {
        if (kt <= qt) {
          bf16x8 kf0 = *(const bf16x8*)&ksm[(h * 128 + kt * 32 + ln31) * 40 + hi * 8];
          bf16x8 kf1 = *(const bf16x8*)&ksm[(h * 128 + kt * 32 + ln31) * 40 + 16 + hi * 8];
          f32x16 z = {};
          z = __builtin_amdgcn_mfma_f32_32x32x16_bf16(kf0, qf0, z, 0, 0, 0);
          s[kt] = __builtin_amdgcn_mfma_f32_32x32x16_bf16(kf1, qf1, z, 0, 0, 0);
        }
      }
      // causal mask (diagonal tile only: key crow > query ln31)
      {
#pragma unroll
        for (int rg = 0; rg < 16; ++rg) {
          const int c_lo = (rg & 3) + 8 * (rg >> 2);
#pragma unroll
          for (int kt = 0; kt < 4; ++kt) {
            if (kt == qt) {
              int crow = c_lo + 4 * hi;
              s[kt][rg] = (crow <= ln31) ? s[kt][rg] : NEGINF;
            }
          }
        }
      }
      // softmax: in-lane + 1 shfl_xor(32) each for max and sum
      float mx = NEGINF;
#pragma unroll
      for (int kt = 0; kt < 4; ++kt)
        if (kt <= qt)
#pragma unroll
          for (int rg = 0; rg < 16; ++rg) mx = fmaxf(mx, s[kt][rg]);
      mx = fmaxf(mx, __shfl_xor(mx, 32));
      float sum = 0.0f;
#pragma unroll
      for (int kt = 0; kt < 4; ++kt)
        if (kt <= qt)
#pragma unroll
          for (int rg = 0; rg < 16; ++rg) {
            s[kt][rg] = __expf(s[kt][rg] - mx);
            sum += s[kt][rg];
          }
      sum += __shfl_xor(sum, 32);
      float inv = 1.0f / sum;
      // normalize in-lane, pack P pairs (keys 2p, 2p+1 of each kt-tile half)
      unsigned pk[4][8];
#pragma unroll
      for (int kt = 0; kt < 4; ++kt) {
        if (kt <= qt) {
#pragma unroll
          for (int p = 0; p < 8; ++p) {
            union { bf16x2 v; unsigned u; } w;
            w.v[0] = (__bf16)(s[kt][2 * p] * inv);
            w.v[1] = (__bf16)(s[kt][2 * p + 1] * inv);
            pk[kt][p] = w.u;
          }
        }
      }
      // PV: A = P (row = query = ln31), frags assembled via 4 shfl_xor(32)
      f32x16 o = {};
#pragma unroll
      for (int kt = 0; kt < 4; ++kt) {
        if (kt <= qt) {
#pragma unroll
          for (int m = 0; m < 2; ++m) {
            unsigned f0 = (unsigned)__shfl_xor((int)pk[kt][4 * m + 0], 32);
            unsigned f1 = (unsigned)__shfl_xor((int)pk[kt][4 * m + 1], 32);
            unsigned f2 = (unsigned)__shfl_xor((int)pk[kt][4 * m + 2], 32);
            unsigned f3 = (unsigned)__shfl_xor((int)pk[kt][4 * m + 3], 32);
            union { unsigned w[4]; bf16x8 v; } Aw;
            Aw.w[0] = hi ? f2 : pk[kt][4 * m + 0];
            Aw.w[1] = hi ? f3 : pk[kt][4 * m + 1];
            Aw.w[2] = hi ? pk[kt][4 * m + 2] : f0;
            Aw.w[3] = hi ? pk[kt][4 * m + 3] : f1;
            bf16x8 vf = *(const bf16x8*)&vT[(h * 32 + ln31) * 128 +
                ((kt * 32 + m * 16 + hi * 8) ^ ((ln31 & 7) << 3))];
            o = __builtin_amdgcn_mfma_f32_32x32x16_bf16(Aw.v, vf, o, 0, 0, 0);
          }
        }
      }
      // store O: col = d = ln31, row = query
#pragma unroll
      for (int rg = 0; rg < 16; ++rg) {
        const int c_lo = (rg & 3) + 8 * (rg >> 2);
        int l = qt * 32 + c_lo + 4 * hi;
        if (l < L_SEQ)
          out[((size_t)b * L_SEQ + l) * 128 + h * 32 + ln31] = o[rg];
      }
    }
  }

  // ======== FC2 + bias + SiLU (verbatim R9; 16x16 path) ========
  __syncthreads();
  {
    const int ln15 = lane & 15, kg = lane >> 4;
    int yr = wv * 16 + ln15;
    if (yr > L_SEQ - 1) yr = L_SEQ - 1;
    const float* yrow = out + ((size_t)b * L_SEQ + yr) * 128;
    bf16x8 af2[4];
#pragma unroll
    for (int kb = 0; kb < 4; ++kb) {
      float4 lo = *(const float4*)&yrow[kb * 32 + kg * 8];
      float4 hi4 = *(const float4*)&yrow[kb * 32 + kg * 8 + 4];
      bf16x8 v;
      v[0] = (__bf16)lo.x; v[1] = (__bf16)lo.y; v[2] = (__bf16)lo.z; v[3] = (__bf16)lo.w;
      v[4] = (__bf16)hi4.x; v[5] = (__bf16)hi4.y; v[6] = (__bf16)hi4.z; v[7] = (__bf16)hi4.w;
      af2[kb] = v;
    }
    float bc[8];
#pragma unroll
    for (int nt = 0; nt < 8; ++nt) bc[nt] = bfc2[nt * 16 + ln15];
    f32x4 acc2[8] = {};
#pragma unroll
    for (int nt = 0; nt < 8; ++nt)
#pragma unroll
      for (int kb = 0; kb < 4; ++kb)
        acc2[nt] = __builtin_amdgcn_mfma_f32_16x16x32_bf16(
            af2[kb], *(const bf16x8*)&Wf2b[(((nt * 4 + kb) * 64) + lane) * 8],
            acc2[nt], 0, 0, 0);
#pragma unroll
    for (int nt = 0; nt < 8; ++nt)
#pragma unroll
      for (int r = 0; r < 4; ++r) {
        int row = wv * 16 + kg * 4 + r, c = nt * 16 + ln15;
        if (row < L_SEQ) {
          float vv = acc2[nt][r] + bc[nt];
          out[((size_t)b * L_SEQ + row) * 128 + c] = vv / (1.0f + __expf(-vv));
        }
      }
  }
}

extern "C" void kernel_launch(void* const* d_in, const int* in_sizes, int n_in,
                              void* d_out, int out_size, void* d_ws,
                              size_t ws_size, hipStream_t stream) {
  const float* x = (const float*)d_in[0];
  const float* Wqkv = (const float*)d_in[1];
  const float* bqkv = (const float*)d_in[2];
  const float* Wfc2 = (const float*)d_in[3];
  const float* bfc2 = (const float*)d_in[4];
  float* out = (float*)d_out;

  char* ws = (char*)d_ws;
  unsigned* tabu = (unsigned*)ws;                        // 30,464 B (pad 30,720)
  __bf16* Wb = (__bf16*)(ws + 30720);                    // 98,304 B
  float* bb2 = (float*)(ws + 30720 + 98304);             //  1,536 B
  __bf16* Wf2b = (__bf16*)(ws + 30720 + 98304 + 1536);   // 32,768 B (end 163,328)

  const int B = in_sizes[0] / (L_SEQ * D_MODEL);  // 2048
  prep_kernel<<<192, 256, 0, stream>>>(Wqkv, bqkv, Wfc2, tabu, Wb, bb2, Wf2b);
  fused_all<<<B, 512, 0, stream>>>(x, Wb, bb2, tabu, Wf2b, bfc2, out);
}